// Round 4
// baseline (288.866 us; speedup 1.0000x reference)
//
#include <hip/hip_runtime.h>

// ---------------------------------------------------------------------------
// Types / helpers
// ---------------------------------------------------------------------------
typedef __bf16 bf16x8 __attribute__((ext_vector_type(8)));
typedef float  f32x4  __attribute__((ext_vector_type(4)));

union U8 { bf16x8 v; __bf16 e[8]; unsigned short u[8]; };

__device__ __forceinline__ unsigned short f2bf(float f) {
  unsigned int u = __float_as_uint(f);
  unsigned int r = (u + 0x7FFFu + ((u >> 16) & 1u)) >> 16;  // RNE
  return (unsigned short)r;
}

__device__ __forceinline__ void async16(const void* g, void* l) {
  __builtin_amdgcn_global_load_lds(
      (__attribute__((address_space(1))) void*)(g),
      (__attribute__((address_space(3))) void*)(l), 16, 0, 0);
}

__device__ __forceinline__ void block_barrier() {
  asm volatile("" ::: "memory");
  __builtin_amdgcn_sched_barrier(0);
  __builtin_amdgcn_s_barrier();
  __builtin_amdgcn_sched_barrier(0);
  asm volatile("" ::: "memory");
}

// ---------------------------------------------------------------------------
// Batched transpose: in fp32 [batch][R][Cc] -> out bf16 [batch*Cc + c][R]
// ---------------------------------------------------------------------------
__global__ __launch_bounds__(256) void transpose_w(
    const float* __restrict__ in, unsigned short* __restrict__ out,
    int R, int Cc) {
  __shared__ float tile[32][33];
  const int batch = blockIdx.z;
  const float* ip = in + (size_t)batch * R * Cc;
  unsigned short* op = out + (size_t)batch * R * Cc;
  const int c0 = blockIdx.x * 32, r0 = blockIdx.y * 32;
  const int tx = threadIdx.x, ty = threadIdx.y;  // 32 x 8
#pragma unroll
  for (int i = 0; i < 32; i += 8)
    tile[ty + i][tx] = ip[(size_t)(r0 + ty + i) * Cc + c0 + tx];
  __syncthreads();
#pragma unroll
  for (int i = 0; i < 32; i += 8)
    op[(size_t)(c0 + ty + i) * R + r0 + tx] = f2bf(tile[tx][ty + i]);
}

// ---------------------------------------------------------------------------
// LayerNorm over rows of 1024, fp32 in -> bf16 out.
// ---------------------------------------------------------------------------
__global__ __launch_bounds__(256) void ln_kernel(
    const float* __restrict__ x, const float* __restrict__ g,
    const float* __restrict__ bta, unsigned short* __restrict__ out) {
  const int C = 1024;
  const int row = blockIdx.x, tid = threadIdx.x;
  const float4 v = ((const float4*)(x + (size_t)row * C))[tid];
  float s  = v.x + v.y + v.z + v.w;
  float ss = v.x * v.x + v.y * v.y + v.z * v.z + v.w * v.w;
#pragma unroll
  for (int off = 32; off > 0; off >>= 1) {
    s  += __shfl_down(s, off);
    ss += __shfl_down(ss, off);
  }
  __shared__ float r0[4], r1[4];
  const int wave = tid >> 6, lane = tid & 63;
  if (lane == 0) { r0[wave] = s; r1[wave] = ss; }
  __syncthreads();
  s  = r0[0] + r0[1] + r0[2] + r0[3];
  ss = r1[0] + r1[1] + r1[2] + r1[3];
  const float mu   = s * (1.0f / C);
  const float var  = ss * (1.0f / C) - mu * mu;
  const float rstd = rsqrtf(var + 1e-5f);
  const float4 gv = ((const float4*)g)[tid];
  const float4 bv = ((const float4*)bta)[tid];
  ushort4 o;
  o.x = f2bf((v.x - mu) * rstd * gv.x + bv.x);
  o.y = f2bf((v.y - mu) * rstd * gv.y + bv.y);
  o.z = f2bf((v.z - mu) * rstd * gv.z + bv.z);
  o.w = f2bf((v.w - mu) * rstd * gv.w + bv.w);
  ((ushort4*)(out + (size_t)row * C))[tid] = o;
}

// ---------------------------------------------------------------------------
// 128x128 2-phase GEMM (kept for N=1024 shapes): C = A[M][K] * BT[N][K]^T.
// 1D grid with XCD-bijective swizzle + GROUP_M=4 supertiling.
// EPI: 1 = +bias+resid -> fp32 ; 3 = +bias+resid -> fp32
// ---------------------------------------------------------------------------
template <int EPI>
__global__ __launch_bounds__(256, 2) void gemm_bt(
    const unsigned short* __restrict__ A, const unsigned short* __restrict__ BT,
    void* __restrict__ Cout, const float* __restrict__ bias,
    const float* __restrict__ resid, int M, int N, int K) {
  __shared__ __align__(16) unsigned short As[128 * 32];
  __shared__ __align__(16) unsigned short Bs[128 * 32];
  const int tid = threadIdx.x;
  const int lane = tid & 63, wave = tid >> 6;
  const int wrow = wave >> 1, wcol = wave & 1;
  const int lr = lane & 15, lg = lane >> 4;

  // XCD swizzle + GROUP_M=4 (nwg % 8 == 0, Mtiles % 4 == 0 required)
  const int nwg = gridDim.x;
  const int cpx = nwg >> 3;
  const int swz = ((int)blockIdx.x & 7) * cpx + ((int)blockIdx.x >> 3);
  const int Nt = N >> 7;
  const int g4 = swz / (4 * Nt);
  const int rem = swz - g4 * 4 * Nt;
  const int m0 = (g4 * 4 + (rem & 3)) << 7;
  const int n0 = (rem >> 2) << 7;

  f32x4 acc[4][4] = {};

  const int srow = tid >> 2, k8 = (tid & 3) << 3;
  const size_t arow0 = (size_t)(m0 + srow) * K + k8;
  const size_t brow0 = (size_t)(n0 + srow) * K + k8;
  const size_t skip64 = (size_t)64 * K;

  for (int kt = 0; kt < K; kt += 32) {
    async16(A + arow0 + kt, As + tid * 8);
    async16(A + arow0 + skip64 + kt, As + tid * 8 + 2048);
    async16(BT + brow0 + kt, Bs + tid * 8);
    async16(BT + brow0 + skip64 + kt, Bs + tid * 8 + 2048);
    __syncthreads();
    bf16x8 af[4], bfr[4];
#pragma unroll
    for (int i = 0; i < 4; i++)
      af[i] = *(const bf16x8*)(As + (wrow * 64 + i * 16 + lr) * 32 + lg * 8);
#pragma unroll
    for (int j = 0; j < 4; j++)
      bfr[j] = *(const bf16x8*)(Bs + (wcol * 64 + j * 16 + lr) * 32 + lg * 8);
#pragma unroll
    for (int i = 0; i < 4; i++)
#pragma unroll
      for (int j = 0; j < 4; j++)
        acc[i][j] =
            __builtin_amdgcn_mfma_f32_16x16x32_bf16(af[i], bfr[j], acc[i][j], 0, 0, 0);
    __syncthreads();
  }

#pragma unroll
  for (int j = 0; j < 4; j++) {
    const int col = n0 + wcol * 64 + j * 16 + lr;
    const float bv = bias[col];
#pragma unroll
    for (int i = 0; i < 4; i++) {
      const int row0 = m0 + wrow * 64 + i * 16 + lg * 4;
#pragma unroll
      for (int r = 0; r < 4; r++) {
        const size_t idx = (size_t)(row0 + r) * N + col;
        ((float*)Cout)[idx] = acc[i][j][r] + bv + resid[idx];
      }
    }
  }
}

// ---------------------------------------------------------------------------
// 256x256 8-phase deep-pipelined GEMM (HK/m201-style, plain HIP).
// BK=64 split in two k-halves; LDS As/Bs[2 buf][2 khalf][256x32] (128 KiB).
// 8 waves (2M x 4N), per-wave 128x64 out (acc[8][4]). 4 phases per K-tile:
//   ph(ks,mh): {ds_read frags, stage 1 half-tile (2 gload_lds), barrier,
//               setprio(1), 16 MFMA, setprio(0), barrier}
// Stage schedule in tile t: ph1 Akh1(t+1), ph2 Bkh1(t+1), ph3 Akh0(t+2),
// ph4 Bkh0(t+2); boundary s_waitcnt vmcnt(4) (never 0 mid-loop).
// LDS XOR swizzle: global source pre-swizzled chunk^=(row>>1)&3 (rule 21);
// reads use chunk = lg ^ ((lr>>1)&3) -> each frag read is a permuted
// contiguous 1KB region => conflict-free.
// EPI: 2 = relu(+bias) -> bf16 ; 4 = QKV split (col<2048 -> Cout[M][2048],
//      else transposed Cout2[(col-2048)][4096])
// ---------------------------------------------------------------------------
template <int EPI>
__global__ __launch_bounds__(512, 2) void gemm8p(
    const unsigned short* __restrict__ A, const unsigned short* __restrict__ BT,
    void* __restrict__ Cout, void* __restrict__ Cout2,
    const float* __restrict__ bias, int M, int N, int K) {
  __shared__ __align__(16) unsigned short As[2][2][8192];
  __shared__ __align__(16) unsigned short Bs[2][2][8192];
  const int tid = threadIdx.x;
  const int lane = tid & 63;
  const int wave = tid >> 6;
  const int wm = wave >> 2, wn = wave & 3;  // 2 x 4 wave grid
  const int lr = lane & 15, lg = lane >> 4;

  // XCD swizzle + GROUP_M=4 (nwg % 8 == 0, Mtiles % 4 == 0)
  const int nwg = gridDim.x;
  const int cpx = nwg >> 3;
  const int swz = ((int)blockIdx.x & 7) * cpx + ((int)blockIdx.x >> 3);
  const int Nt = N >> 8;
  const int g4 = swz / (4 * Nt);
  const int rem = swz - g4 * 4 * Nt;
  const int m0 = (g4 * 4 + (rem & 3)) << 8;
  const int n0 = (rem >> 2) << 8;

  // staging: thread t covers rows {t>>2, 128+(t>>2)} of the 256-row tile,
  // 16B chunk (t&3), global chunk pre-swizzled so LDS linear = swizzled.
  const int srow = tid >> 2;
  const int scg = ((tid & 3) ^ ((srow >> 1) & 3)) << 3;
  const unsigned short* Ag = A + (size_t)(m0 + srow) * K + scg;
  const unsigned short* Bg = BT + (size_t)(n0 + srow) * K + scg;
  const size_t rskip = (size_t)128 * K;
  const int l8 = tid * 8;

  // frag-read swizzled k-chunk (element offset within a 32-elem k-half row)
  const int kch = (lg ^ ((lr >> 1) & 3)) << 3;

  f32x4 acc[8][4] = {};
  bf16x8 afr[4], bfr[4];
  const int nkt = K >> 6;

  // ---- prologue: stage tile0 kh0,kh1 and tile1 kh0 (6 half-tiles)
  async16(Ag, &As[0][0][l8]);            async16(Ag + rskip, &As[0][0][l8 + 4096]);
  async16(Bg, &Bs[0][0][l8]);            async16(Bg + rskip, &Bs[0][0][l8 + 4096]);
  async16(Ag + 32, &As[0][1][l8]);       async16(Ag + 32 + rskip, &As[0][1][l8 + 4096]);
  async16(Bg + 32, &Bs[0][1][l8]);       async16(Bg + 32 + rskip, &Bs[0][1][l8 + 4096]);
  async16(Ag + 64, &As[1][0][l8]);       async16(Ag + 64 + rskip, &As[1][0][l8 + 4096]);
  async16(Bg + 64, &Bs[1][0][l8]);       async16(Bg + 64 + rskip, &Bs[1][0][l8 + 4096]);
  asm volatile("s_waitcnt vmcnt(4)" ::: "memory");
  block_barrier();

  for (int t = 0; t < nkt; ++t) {
    const int buf = t & 1, nbuf = buf ^ 1;
    const int kt1 = (t + 1) << 6, kt2 = (t + 2) << 6;
    const bool s1 = (t + 1 < nkt), s2 = (t + 2 < nkt);

    // ---- phase 1: ks=0, mh=0 ----
#pragma unroll
    for (int fm = 0; fm < 4; fm++)
      afr[fm] = *(const bf16x8*)&As[buf][0][(wm * 128 + fm * 16 + lr) * 32 + kch];
#pragma unroll
    for (int fn = 0; fn < 4; fn++)
      bfr[fn] = *(const bf16x8*)&Bs[buf][0][(wn * 64 + fn * 16 + lr) * 32 + kch];
    if (s1) {
      async16(Ag + kt1 + 32, &As[nbuf][1][l8]);
      async16(Ag + kt1 + 32 + rskip, &As[nbuf][1][l8 + 4096]);
    }
    block_barrier();
    __builtin_amdgcn_s_setprio(1);
#pragma unroll
    for (int fm = 0; fm < 4; fm++)
#pragma unroll
      for (int fn = 0; fn < 4; fn++)
        acc[fm][fn] = __builtin_amdgcn_mfma_f32_16x16x32_bf16(afr[fm], bfr[fn], acc[fm][fn], 0, 0, 0);
    __builtin_amdgcn_s_setprio(0);
    block_barrier();

    // ---- phase 2: ks=0, mh=1 ----
#pragma unroll
    for (int fm = 0; fm < 4; fm++)
      afr[fm] = *(const bf16x8*)&As[buf][0][(wm * 128 + 64 + fm * 16 + lr) * 32 + kch];
    if (s1) {
      async16(Bg + kt1 + 32, &Bs[nbuf][1][l8]);
      async16(Bg + kt1 + 32 + rskip, &Bs[nbuf][1][l8 + 4096]);
    }
    block_barrier();
    __builtin_amdgcn_s_setprio(1);
#pragma unroll
    for (int fm = 0; fm < 4; fm++)
#pragma unroll
      for (int fn = 0; fn < 4; fn++)
        acc[4 + fm][fn] = __builtin_amdgcn_mfma_f32_16x16x32_bf16(afr[fm], bfr[fn], acc[4 + fm][fn], 0, 0, 0);
    __builtin_amdgcn_s_setprio(0);
    block_barrier();

    // ---- phase 3: ks=1, mh=0 ----
#pragma unroll
    for (int fm = 0; fm < 4; fm++)
      afr[fm] = *(const bf16x8*)&As[buf][1][(wm * 128 + fm * 16 + lr) * 32 + kch];
#pragma unroll
    for (int fn = 0; fn < 4; fn++)
      bfr[fn] = *(const bf16x8*)&Bs[buf][1][(wn * 64 + fn * 16 + lr) * 32 + kch];
    if (s2) {
      async16(Ag + kt2, &As[buf][0][l8]);
      async16(Ag + kt2 + rskip, &As[buf][0][l8 + 4096]);
    }
    block_barrier();
    __builtin_amdgcn_s_setprio(1);
#pragma unroll
    for (int fm = 0; fm < 4; fm++)
#pragma unroll
      for (int fn = 0; fn < 4; fn++)
        acc[fm][fn] = __builtin_amdgcn_mfma_f32_16x16x32_bf16(afr[fm], bfr[fn], acc[fm][fn], 0, 0, 0);
    __builtin_amdgcn_s_setprio(0);
    block_barrier();

    // ---- phase 4: ks=1, mh=1 ----
#pragma unroll
    for (int fm = 0; fm < 4; fm++)
      afr[fm] = *(const bf16x8*)&As[buf][1][(wm * 128 + 64 + fm * 16 + lr) * 32 + kch];
    if (s2) {
      async16(Bg + kt2, &Bs[buf][0][l8]);
      async16(Bg + kt2 + rskip, &Bs[buf][0][l8 + 4096]);
    }
    block_barrier();
    __builtin_amdgcn_s_setprio(1);
#pragma unroll
    for (int fm = 0; fm < 4; fm++)
#pragma unroll
      for (int fn = 0; fn < 4; fn++)
        acc[4 + fm][fn] = __builtin_amdgcn_mfma_f32_16x16x32_bf16(afr[fm], bfr[fn], acc[4 + fm][fn], 0, 0, 0);
    __builtin_amdgcn_s_setprio(0);
    // boundary: keep tile t+2's kh0 pair (4 loads) in flight; drain at tail
    if (s2) asm volatile("s_waitcnt vmcnt(4)" ::: "memory");
    else    asm volatile("s_waitcnt vmcnt(0)" ::: "memory");
    block_barrier();
  }

  // ---- epilogue ----
#pragma unroll
  for (int fn = 0; fn < 4; fn++) {
    const int col = n0 + wn * 64 + fn * 16 + lr;
    float bv = 0.0f;
    if (EPI == 2) bv = bias[col];
#pragma unroll
    for (int fm = 0; fm < 8; fm++) {
      const int row0 = m0 + wm * 128 + fm * 16 + lg * 4;
      if (EPI == 2) {
#pragma unroll
        for (int r = 0; r < 4; r++)
          ((unsigned short*)Cout)[(size_t)(row0 + r) * N + col] =
              f2bf(fmaxf(acc[fm][fn][r] + bv, 0.0f));
      } else {  // EPI 4: QKV split
        if (col < 2048) {
#pragma unroll
          for (int r = 0; r < 4; r++)
            ((unsigned short*)Cout)[(size_t)(row0 + r) * 2048 + col] =
                f2bf(acc[fm][fn][r]);
        } else {
          ushort4 ov;
          ov.x = f2bf(acc[fm][fn][0]);
          ov.y = f2bf(acc[fm][fn][1]);
          ov.z = f2bf(acc[fm][fn][2]);
          ov.w = f2bf(acc[fm][fn][3]);
          *(ushort4*)((unsigned short*)Cout2 + (size_t)(col - 2048) * 4096 + row0) = ov;
        }
      }
    }
  }
}

// ---------------------------------------------------------------------------
// Flash attention (causal), swapped-operand, LDS-staged K/V, double-buffered.
// (unchanged from round 3)
// ---------------------------------------------------------------------------
__global__ __launch_bounds__(256) void attn_kernel(
    const unsigned short* __restrict__ qk, const unsigned short* __restrict__ vT,
    unsigned short* __restrict__ o) {
  const int T = 2048, C = 1024, QKS = 2048;
  const int tid = threadIdx.x;
  const int wave = tid >> 6, lane = tid & 63;
  const int lr = lane & 15, lg = lane >> 4;
  const int b = blockIdx.y >> 4, hh = blockIdx.y & 15;
  const size_t rowb = (size_t)b * T * QKS;
  const int qcol = hh * 64;
  const int kcol = 1024 + hh * 64;
  const int vrow0 = hh * 64;
  const size_t bT = (size_t)b * T;
  const int swe = (lr & 7) << 3;

  __shared__ __align__(16) unsigned short Ks[2][64 * 64];
  __shared__ __align__(16) unsigned short Vs[2][64 * 64];
  __shared__ __align__(16) unsigned short Ps[4][16][72];

  const int rw = tid >> 3;
  const int c8 = ((tid & 7) ^ (rw & 7)) << 3;

#pragma unroll 1
  for (int pass = 0; pass < 2; ++pass) {
    const int qt = (pass == 0) ? (int)blockIdx.x : (31 - (int)blockIdx.x);
    const int qbase = qt * 64 + wave * 16;
    const int trow = qbase + lr;

    U8 qf[2];
#pragma unroll
    for (int j = 0; j < 2; j++)
      qf[j].v = *(const bf16x8*)(qk + rowb + (size_t)trow * QKS + qcol + j * 32 + lg * 8);
    asm volatile("s_waitcnt vmcnt(0)" ::: "memory");

    async16(qk + rowb + (size_t)rw * QKS + kcol + c8, Ks[0] + tid * 8);
    async16(qk + rowb + (size_t)(32 + rw) * QKS + kcol + c8, Ks[0] + 2048 + tid * 8);
    async16(vT + (size_t)(vrow0 + rw) * 4096 + bT + c8, Vs[0] + tid * 8);
    async16(vT + (size_t)(vrow0 + 32 + rw) * 4096 + bT + c8, Vs[0] + 2048 + tid * 8);

    f32x4 oa[4] = {};
    float mrun = -1e30f, lsum = 0.0f;
    int cur = 0;

    for (int sb = 0; sb <= qt; ++sb) {
      if (sb < qt) {
        const int s1 = (sb + 1) * 64;
        const int nb = cur ^ 1;
        async16(qk + rowb + (size_t)(s1 + rw) * QKS + kcol + c8, Ks[nb] + tid * 8);
        async16(qk + rowb + (size_t)(s1 + 32 + rw) * QKS + kcol + c8, Ks[nb] + 2048 + tid * 8);
        async16(vT + (size_t)(vrow0 + rw) * 4096 + bT + s1 + c8, Vs[nb] + tid * 8);
        async16(vT + (size_t)(vrow0 + 32 + rw) * 4096 + bT + s1 + c8, Vs[nb] + 2048 + tid * 8);
        asm volatile("s_waitcnt vmcnt(4)" ::: "memory");
      } else {
        asm volatile("s_waitcnt vmcnt(0)" ::: "memory");
      }
      block_barrier();

      const unsigned short* Kc = Ks[cur];
      const unsigned short* Vc = Vs[cur];
      const int s0 = sb * 64;

      f32x4 sa[4] = {};
#pragma unroll
      for (int j = 0; j < 2; j++) {
#pragma unroll
        for (int mf = 0; mf < 4; mf++) {
          U8 kf;
          kf.v = *(const bf16x8*)(Kc + (mf * 16 + lr) * 64 + ((j * 32 + lg * 8) ^ swe));
          sa[mf] = __builtin_amdgcn_mfma_f32_16x16x32_bf16(kf.v, qf[j].v, sa[mf], 0, 0, 0);
        }
      }
      float sv[16];
#pragma unroll
      for (int mf = 0; mf < 4; mf++)
#pragma unroll
        for (int r = 0; r < 4; r++) sv[mf * 4 + r] = sa[mf][r] * 0.125f;

      if (sb == qt) {
#pragma unroll
        for (int mf = 0; mf < 4; mf++)
#pragma unroll
          for (int r = 0; r < 4; r++)
            if (s0 + mf * 16 + lg * 4 + r > trow) sv[mf * 4 + r] = -1e30f;
      }

      float tm = sv[0];
#pragma unroll
      for (int i = 1; i < 16; i++) tm = fmaxf(tm, sv[i]);
      tm = fmaxf(tm, __shfl_xor(tm, 16));
      tm = fmaxf(tm, __shfl_xor(tm, 32));

      if (!__all(tm <= mrun + 8.0f)) {
        const float mn = fmaxf(mrun, tm);
        const float corr = __expf(mrun - mn);
        lsum *= corr;
#pragma unroll
        for (int c = 0; c < 4; c++)
#pragma unroll
          for (int r = 0; r < 4; r++) oa[c][r] *= corr;
        mrun = mn;
      }

      float rs = 0.0f;
#pragma unroll
      for (int i = 0; i < 16; i++) {
        sv[i] = __expf(sv[i] - mrun);
        rs += sv[i];
      }
      rs += __shfl_xor(rs, 16);
      rs += __shfl_xor(rs, 32);
      lsum += rs;

#pragma unroll
      for (int mf = 0; mf < 4; mf++) {
        ushort4 w;
        w.x = f2bf(sv[mf * 4 + 0]);
        w.y = f2bf(sv[mf * 4 + 1]);
        w.z = f2bf(sv[mf * 4 + 2]);
        w.w = f2bf(sv[mf * 4 + 3]);
        *(ushort4*)&Ps[wave][lr][mf * 16 + lg * 4] = w;
      }
      asm volatile("" ::: "memory");
      U8 pb[2];
      pb[0].v = *(const bf16x8*)&Ps[wave][lr][lg * 8];
      pb[1].v = *(const bf16x8*)&Ps[wave][lr][32 + lg * 8];
      asm volatile("" ::: "memory");

#pragma unroll
      for (int c = 0; c < 4; c++) {
#pragma unroll
        for (int ks = 0; ks < 2; ks++) {
          U8 vf;
          vf.v = *(const bf16x8*)(Vc + (c * 16 + lr) * 64 + ((ks * 32 + lg * 8) ^ swe));
          oa[c] = __builtin_amdgcn_mfma_f32_16x16x32_bf16(vf.v, pb[ks].v, oa[c], 0, 0, 0);
        }
      }

      block_barrier();
      cur ^= 1;
    }

    const float inv = 1.0f / lsum;
#pragma unroll
    for (int c = 0; c < 4; c++) {
      ushort4 ov;
      ov.x = f2bf(oa[c][0] * inv);
      ov.y = f2bf(oa[c][1] * inv);
      ov.z = f2bf(oa[c][2] * inv);
      ov.w = f2bf(oa[c][3] * inv);
      *(ushort4*)(o + (size_t)(bT + trow) * C + hh * 64 + c * 16 + lg * 4) = ov;
    }
  }
}

// ---------------------------------------------------------------------------
// Orchestration
// ---------------------------------------------------------------------------
extern "C" void kernel_launch(void* const* d_in, const int* in_sizes, int n_in,
                              void* d_out, int out_size, void* d_ws, size_t ws_size,
                              hipStream_t stream) {
  (void)in_sizes; (void)n_in; (void)out_size; (void)ws_size;
  const int T = 2048, C = 1024, M = 2 * T, C4 = 4 * C;

  const float* x     = (const float*)d_in[0];
  const float* Wq    = (const float*)d_in[1];
  const float* Wk    = (const float*)d_in[2];
  const float* Wv    = (const float*)d_in[3];
  const float* Wproj = (const float*)d_in[4];
  const float* bproj = (const float*)d_in[5];
  const float* W1    = (const float*)d_in[6];
  const float* b1    = (const float*)d_in[7];
  const float* W2    = (const float*)d_in[8];
  const float* b2    = (const float*)d_in[9];
  const float* ln1g  = (const float*)d_in[10];
  const float* ln1b  = (const float*)d_in[11];
  const float* ln2g  = (const float*)d_in[12];
  const float* ln2b  = (const float*)d_in[13];
  float* out = (float*)d_out;

  char* ws = (char*)d_ws;
  const size_t MBy = (size_t)1 << 20;
  unsigned short* WqkvT = (unsigned short*)(ws + 0 * MBy);  // 6 MB [3072][1024]
  unsigned short* WqT = WqkvT;
  unsigned short* WkT = WqkvT + 1024 * 1024;
  unsigned short* WvT = WqkvT + 2048 * 1024;
  unsigned short* WpT = (unsigned short*)(ws + 6 * MBy);    // 2 MB
  unsigned short* W1T = (unsigned short*)(ws + 8 * MBy);    // 8 MB
  unsigned short* W2T = (unsigned short*)(ws + 16 * MBy);   // 8 MB
  unsigned short* h   = (unsigned short*)(ws + 24 * MBy);   // 8 MB  [4096][1024]
  unsigned short* qkb = (unsigned short*)(ws + 32 * MBy);   // 16 MB [4096][2048]
  unsigned short* vTb = (unsigned short*)(ws + 48 * MBy);   // 8 MB  [1024][4096]
  unsigned short* att = (unsigned short*)(ws + 56 * MBy);   // 8 MB
  float*          x1  = (float*)(ws + 64 * MBy);            // 16 MB
  unsigned short* h2  = att;                                // reuse
  unsigned short* ff1 = h;                                  // reuse h/qkb/vTb

  const dim3 tb(32, 8);
  transpose_w<<<dim3(2, 32, 16), tb, 0, stream>>>(Wq, WqT, 1024, 64);
  transpose_w<<<dim3(2, 32, 16), tb, 0, stream>>>(Wk, WkT, 1024, 64);
  transpose_w<<<dim3(2, 32, 16), tb, 0, stream>>>(Wv, WvT, 1024, 64);
  transpose_w<<<dim3(32, 32, 1), tb, 0, stream>>>(Wproj, WpT, 1024, 1024);
  transpose_w<<<dim3(128, 32, 1), tb, 0, stream>>>(W1, W1T, 1024, 4096);
  transpose_w<<<dim3(32, 128, 1), tb, 0, stream>>>(W2, W2T, 4096, 1024);

  ln_kernel<<<M, 256, 0, stream>>>(x, ln1g, ln1b, h);

  // Fused QKV (8-phase 256^2): N=3072; cols<2048 -> qkb, cols>=2048 -> vTb^T
  gemm8p<4><<<192, 512, 0, stream>>>(h, WqkvT, qkb, vTb, nullptr, M, 3072, C);

  attn_kernel<<<dim3(16, 32), 256, 0, stream>>>(qkb, vTb, att);

  gemm_bt<1><<<256, 256, 0, stream>>>(att, WpT, x1, bproj, x, M, C, C);

  ln_kernel<<<M, 256, 0, stream>>>(x1, ln2g, ln2b, h2);

  // FFN1 (8-phase 256^2): relu(h2 @ W1 + b1) -> bf16
  gemm8p<2><<<256, 512, 0, stream>>>(h2, W1T, ff1, nullptr, b1, M, C4, C);

  gemm_bt<3><<<256, 256, 0, stream>>>(ff1, W2T, out, b2, x1, M, C, C4);
}

// Round 5
// 267.407 us; speedup vs baseline: 1.0802x; 1.0802x over previous
//
#include <hip/hip_runtime.h>

// ---------------------------------------------------------------------------
// Types / helpers
// ---------------------------------------------------------------------------
typedef __bf16 bf16x8 __attribute__((ext_vector_type(8)));
typedef float  f32x4  __attribute__((ext_vector_type(4)));

union U8 { bf16x8 v; __bf16 e[8]; unsigned short u[8]; };

__device__ __forceinline__ unsigned short f2bf(float f) {
  unsigned int u = __float_as_uint(f);
  unsigned int r = (u + 0x7FFFu + ((u >> 16) & 1u)) >> 16;  // RNE
  return (unsigned short)r;
}

__device__ __forceinline__ void async16(const void* g, void* l) {
  __builtin_amdgcn_global_load_lds(
      (__attribute__((address_space(1))) void*)(g),
      (__attribute__((address_space(3))) void*)(l), 16, 0, 0);
}

__device__ __forceinline__ void block_barrier() {
  asm volatile("" ::: "memory");
  __builtin_amdgcn_sched_barrier(0);
  __builtin_amdgcn_s_barrier();
  __builtin_amdgcn_sched_barrier(0);
  asm volatile("" ::: "memory");
}

// ---------------------------------------------------------------------------
// Batched transpose: in fp32 [batch][R][Cc] -> out bf16 [batch*Cc + c][R]
// ---------------------------------------------------------------------------
__global__ __launch_bounds__(256) void transpose_w(
    const float* __restrict__ in, unsigned short* __restrict__ out,
    int R, int Cc) {
  __shared__ float tile[32][33];
  const int batch = blockIdx.z;
  const float* ip = in + (size_t)batch * R * Cc;
  unsigned short* op = out + (size_t)batch * R * Cc;
  const int c0 = blockIdx.x * 32, r0 = blockIdx.y * 32;
  const int tx = threadIdx.x, ty = threadIdx.y;  // 32 x 8
#pragma unroll
  for (int i = 0; i < 32; i += 8)
    tile[ty + i][tx] = ip[(size_t)(r0 + ty + i) * Cc + c0 + tx];
  __syncthreads();
#pragma unroll
  for (int i = 0; i < 32; i += 8)
    op[(size_t)(c0 + ty + i) * R + r0 + tx] = f2bf(tile[tx][ty + i]);
}

// ---------------------------------------------------------------------------
// LayerNorm over rows of 1024, fp32 in -> bf16 out.
// ---------------------------------------------------------------------------
__global__ __launch_bounds__(256) void ln_kernel(
    const float* __restrict__ x, const float* __restrict__ g,
    const float* __restrict__ bta, unsigned short* __restrict__ out) {
  const int C = 1024;
  const int row = blockIdx.x, tid = threadIdx.x;
  const float4 v = ((const float4*)(x + (size_t)row * C))[tid];
  float s  = v.x + v.y + v.z + v.w;
  float ss = v.x * v.x + v.y * v.y + v.z * v.z + v.w * v.w;
#pragma unroll
  for (int off = 32; off > 0; off >>= 1) {
    s  += __shfl_down(s, off);
    ss += __shfl_down(ss, off);
  }
  __shared__ float r0[4], r1[4];
  const int wave = tid >> 6, lane = tid & 63;
  if (lane == 0) { r0[wave] = s; r1[wave] = ss; }
  __syncthreads();
  s  = r0[0] + r0[1] + r0[2] + r0[3];
  ss = r1[0] + r1[1] + r1[2] + r1[3];
  const float mu   = s * (1.0f / C);
  const float var  = ss * (1.0f / C) - mu * mu;
  const float rstd = rsqrtf(var + 1e-5f);
  const float4 gv = ((const float4*)g)[tid];
  const float4 bv = ((const float4*)bta)[tid];
  ushort4 o;
  o.x = f2bf((v.x - mu) * rstd * gv.x + bv.x);
  o.y = f2bf((v.y - mu) * rstd * gv.y + bv.y);
  o.z = f2bf((v.z - mu) * rstd * gv.z + bv.z);
  o.w = f2bf((v.w - mu) * rstd * gv.w + bv.w);
  ((ushort4*)(out + (size_t)row * C))[tid] = o;
}

// ---------------------------------------------------------------------------
// 128x128 latency-pipelined GEMM for 1-block/CU shapes (N=1024):
// C[M][N] = A[M][K]*BT[N][K]^T + bias + resid -> fp32.
// BK=64, TRIPLE-buffered LDS (96 KB), 2-tiles-ahead prefetch, counted
// vmcnt(8) (never 0 mid-loop), ONE barrier per K-tile.
// LDS chunk-XOR swizzle via pre-swizzled global source (linear LDS dest,
// rule 21): slot s in a 128x(8x16B) tile holds (row=s>>3, chunk=(s&7)^(row&7)).
// Read side: chunk = (kh*4+lg) ^ (lr&7) -> uniform bank spread (b128 floor).
// XCD-bijective swizzle + GROUP_M=4 supertiling on a 1D grid.
// ---------------------------------------------------------------------------
__global__ __launch_bounds__(256, 1) void gemm_pipe(
    const unsigned short* __restrict__ A, const unsigned short* __restrict__ BT,
    float* __restrict__ Cout, const float* __restrict__ bias,
    const float* __restrict__ resid, int M, int N, int K) {
  __shared__ __align__(16) unsigned short As[3][8192];
  __shared__ __align__(16) unsigned short Bs[3][8192];
  const int tid = threadIdx.x;
  const int lane = tid & 63, wave = tid >> 6;
  const int wrow = wave >> 1, wcol = wave & 1;
  const int lr = lane & 15, lg = lane >> 4;

  // XCD swizzle + GROUP_M=4 (nwg % 8 == 0, Mtiles % 4 == 0 required)
  const int nwg = gridDim.x;
  const int cpx = nwg >> 3;
  const int swz = ((int)blockIdx.x & 7) * cpx + ((int)blockIdx.x >> 3);
  const int Nt = N >> 7;
  const int g4 = swz / (4 * Nt);
  const int rem = swz - g4 * 4 * Nt;
  const int m0 = (g4 * 4 + (rem & 3)) << 7;
  const int n0 = (rem >> 2) << 7;

  // staging geometry: thread covers rows {srow, srow+32, +64, +96}, one 16B
  // chunk each; global chunk pre-swizzled so linear LDS = swizzled layout.
  const int srow = tid >> 3;
  const int sc = ((tid & 7) ^ (srow & 7)) << 3;
  const unsigned short* Ag = A + (size_t)(m0 + srow) * K + sc;
  const unsigned short* Bg = BT + (size_t)(n0 + srow) * K + sc;
  const size_t rskip = (size_t)32 * K;

  f32x4 acc[4][4] = {};
  const int nkt = K >> 6;

#define STAGE_PIPE(T, B)                                              \
  {                                                                   \
    const int kt_ = (T) << 6;                                         \
    _Pragma("unroll")                                                 \
    for (int j = 0; j < 4; ++j) {                                     \
      async16(Ag + kt_ + (size_t)j * rskip, &As[B][j * 2048 + tid * 8]); \
      async16(Bg + kt_ + (size_t)j * rskip, &Bs[B][j * 2048 + tid * 8]); \
    }                                                                 \
  }

  // prologue: stage tiles 0 and 1
  STAGE_PIPE(0, 0);
  STAGE_PIPE(1, 1);

  for (int t = 0; t < nkt; ++t) {
    int buf = t % 3;
    // wait for tile t (own wave's 8 loads beyond the newest 8), then sync
    if (t + 1 < nkt) asm volatile("s_waitcnt vmcnt(8)" ::: "memory");
    else             asm volatile("s_waitcnt vmcnt(0)" ::: "memory");
    block_barrier();
    if (t + 2 < nkt) {
      int sbuf = buf + 2; if (sbuf >= 3) sbuf -= 3;
      STAGE_PIPE(t + 2, sbuf);
    }
#pragma unroll
    for (int kh = 0; kh < 2; ++kh) {
      bf16x8 afr[4], bfr[4];
#pragma unroll
      for (int fm = 0; fm < 4; fm++)
        afr[fm] = *(const bf16x8*)&As[buf][(wrow * 64 + fm * 16 + lr) * 64 +
                                           (((kh * 4 + lg) ^ (lr & 7)) << 3)];
#pragma unroll
      for (int fn = 0; fn < 4; fn++)
        bfr[fn] = *(const bf16x8*)&Bs[buf][(wcol * 64 + fn * 16 + lr) * 64 +
                                           (((kh * 4 + lg) ^ (lr & 7)) << 3)];
#pragma unroll
      for (int fm = 0; fm < 4; fm++)
#pragma unroll
        for (int fn = 0; fn < 4; fn++)
          acc[fm][fn] = __builtin_amdgcn_mfma_f32_16x16x32_bf16(
              afr[fm], bfr[fn], acc[fm][fn], 0, 0, 0);
    }
  }
#undef STAGE_PIPE

#pragma unroll
  for (int fn = 0; fn < 4; fn++) {
    const int col = n0 + wcol * 64 + fn * 16 + lr;
    const float bv = bias[col];
#pragma unroll
    for (int fm = 0; fm < 4; fm++) {
      const int row0 = m0 + wrow * 64 + fm * 16 + lg * 4;
#pragma unroll
      for (int r = 0; r < 4; r++) {
        const size_t idx = (size_t)(row0 + r) * N + col;
        Cout[idx] = acc[fm][fn][r] + bv + resid[idx];
      }
    }
  }
}

// ---------------------------------------------------------------------------
// 256x256 8-phase deep-pipelined GEMM (unchanged from round 4).
// EPI: 2 = relu(+bias) -> bf16 ; 4 = QKV split
// ---------------------------------------------------------------------------
template <int EPI>
__global__ __launch_bounds__(512, 2) void gemm8p(
    const unsigned short* __restrict__ A, const unsigned short* __restrict__ BT,
    void* __restrict__ Cout, void* __restrict__ Cout2,
    const float* __restrict__ bias, int M, int N, int K) {
  __shared__ __align__(16) unsigned short As[2][2][8192];
  __shared__ __align__(16) unsigned short Bs[2][2][8192];
  const int tid = threadIdx.x;
  const int lane = tid & 63;
  const int wave = tid >> 6;
  const int wm = wave >> 2, wn = wave & 3;  // 2 x 4 wave grid
  const int lr = lane & 15, lg = lane >> 4;

  const int nwg = gridDim.x;
  const int cpx = nwg >> 3;
  const int swz = ((int)blockIdx.x & 7) * cpx + ((int)blockIdx.x >> 3);
  const int Nt = N >> 8;
  const int g4 = swz / (4 * Nt);
  const int rem = swz - g4 * 4 * Nt;
  const int m0 = (g4 * 4 + (rem & 3)) << 8;
  const int n0 = (rem >> 2) << 8;

  const int srow = tid >> 2;
  const int scg = ((tid & 3) ^ ((srow >> 1) & 3)) << 3;
  const unsigned short* Ag = A + (size_t)(m0 + srow) * K + scg;
  const unsigned short* Bg = BT + (size_t)(n0 + srow) * K + scg;
  const size_t rskip = (size_t)128 * K;
  const int l8 = tid * 8;

  const int kch = (lg ^ ((lr >> 1) & 3)) << 3;

  f32x4 acc[8][4] = {};
  bf16x8 afr[4], bfr[4];
  const int nkt = K >> 6;

  async16(Ag, &As[0][0][l8]);            async16(Ag + rskip, &As[0][0][l8 + 4096]);
  async16(Bg, &Bs[0][0][l8]);            async16(Bg + rskip, &Bs[0][0][l8 + 4096]);
  async16(Ag + 32, &As[0][1][l8]);       async16(Ag + 32 + rskip, &As[0][1][l8 + 4096]);
  async16(Bg + 32, &Bs[0][1][l8]);       async16(Bg + 32 + rskip, &Bs[0][1][l8 + 4096]);
  async16(Ag + 64, &As[1][0][l8]);       async16(Ag + 64 + rskip, &As[1][0][l8 + 4096]);
  async16(Bg + 64, &Bs[1][0][l8]);       async16(Bg + 64 + rskip, &Bs[1][0][l8 + 4096]);
  asm volatile("s_waitcnt vmcnt(4)" ::: "memory");
  block_barrier();

  for (int t = 0; t < nkt; ++t) {
    const int buf = t & 1, nbuf = buf ^ 1;
    const int kt1 = (t + 1) << 6, kt2 = (t + 2) << 6;
    const bool s1 = (t + 1 < nkt), s2 = (t + 2 < nkt);

    // ---- phase 1: ks=0, mh=0 ----
#pragma unroll
    for (int fm = 0; fm < 4; fm++)
      afr[fm] = *(const bf16x8*)&As[buf][0][(wm * 128 + fm * 16 + lr) * 32 + kch];
#pragma unroll
    for (int fn = 0; fn < 4; fn++)
      bfr[fn] = *(const bf16x8*)&Bs[buf][0][(wn * 64 + fn * 16 + lr) * 32 + kch];
    if (s1) {
      async16(Ag + kt1 + 32, &As[nbuf][1][l8]);
      async16(Ag + kt1 + 32 + rskip, &As[nbuf][1][l8 + 4096]);
    }
    block_barrier();
    __builtin_amdgcn_s_setprio(1);
#pragma unroll
    for (int fm = 0; fm < 4; fm++)
#pragma unroll
      for (int fn = 0; fn < 4; fn++)
        acc[fm][fn] = __builtin_amdgcn_mfma_f32_16x16x32_bf16(afr[fm], bfr[fn], acc[fm][fn], 0, 0, 0);
    __builtin_amdgcn_s_setprio(0);
    block_barrier();

    // ---- phase 2: ks=0, mh=1 ----
#pragma unroll
    for (int fm = 0; fm < 4; fm++)
      afr[fm] = *(const bf16x8*)&As[buf][0][(wm * 128 + 64 + fm * 16 + lr) * 32 + kch];
    if (s1) {
      async16(Bg + kt1 + 32, &Bs[nbuf][1][l8]);
      async16(Bg + kt1 + 32 + rskip, &Bs[nbuf][1][l8 + 4096]);
    }
    block_barrier();
    __builtin_amdgcn_s_setprio(1);
#pragma unroll
    for (int fm = 0; fm < 4; fm++)
#pragma unroll
      for (int fn = 0; fn < 4; fn++)
        acc[4 + fm][fn] = __builtin_amdgcn_mfma_f32_16x16x32_bf16(afr[fm], bfr[fn], acc[4 + fm][fn], 0, 0, 0);
    __builtin_amdgcn_s_setprio(0);
    block_barrier();

    // ---- phase 3: ks=1, mh=0 ----
#pragma unroll
    for (int fm = 0; fm < 4; fm++)
      afr[fm] = *(const bf16x8*)&As[buf][1][(wm * 128 + fm * 16 + lr) * 32 + kch];
#pragma unroll
    for (int fn = 0; fn < 4; fn++)
      bfr[fn] = *(const bf16x8*)&Bs[buf][1][(wn * 64 + fn * 16 + lr) * 32 + kch];
    if (s2) {
      async16(Ag + kt2, &As[buf][0][l8]);
      async16(Ag + kt2 + rskip, &As[buf][0][l8 + 4096]);
    }
    block_barrier();
    __builtin_amdgcn_s_setprio(1);
#pragma unroll
    for (int fm = 0; fm < 4; fm++)
#pragma unroll
      for (int fn = 0; fn < 4; fn++)
        acc[fm][fn] = __builtin_amdgcn_mfma_f32_16x16x32_bf16(afr[fm], bfr[fn], acc[fm][fn], 0, 0, 0);
    __builtin_amdgcn_s_setprio(0);
    block_barrier();

    // ---- phase 4: ks=1, mh=1 ----
#pragma unroll
    for (int fm = 0; fm < 4; fm++)
      afr[fm] = *(const bf16x8*)&As[buf][1][(wm * 128 + 64 + fm * 16 + lr) * 32 + kch];
    if (s2) {
      async16(Bg + kt2, &Bs[buf][0][l8]);
      async16(Bg + kt2 + rskip, &Bs[buf][0][l8 + 4096]);
    }
    block_barrier();
    __builtin_amdgcn_s_setprio(1);
#pragma unroll
    for (int fm = 0; fm < 4; fm++)
#pragma unroll
      for (int fn = 0; fn < 4; fn++)
        acc[4 + fm][fn] = __builtin_amdgcn_mfma_f32_16x16x32_bf16(afr[fm], bfr[fn], acc[4 + fm][fn], 0, 0, 0);
    __builtin_amdgcn_s_setprio(0);
    if (s2) asm volatile("s_waitcnt vmcnt(4)" ::: "memory");
    else    asm volatile("s_waitcnt vmcnt(0)" ::: "memory");
    block_barrier();
  }

#pragma unroll
  for (int fn = 0; fn < 4; fn++) {
    const int col = n0 + wn * 64 + fn * 16 + lr;
    float bv = 0.0f;
    if (EPI == 2) bv = bias[col];
#pragma unroll
    for (int fm = 0; fm < 8; fm++) {
      const int row0 = m0 + wm * 128 + fm * 16 + lg * 4;
      if (EPI == 2) {
#pragma unroll
        for (int r = 0; r < 4; r++)
          ((unsigned short*)Cout)[(size_t)(row0 + r) * N + col] =
              f2bf(fmaxf(acc[fm][fn][r] + bv, 0.0f));
      } else {  // EPI 4: QKV split
        if (col < 2048) {
#pragma unroll
          for (int r = 0; r < 4; r++)
            ((unsigned short*)Cout)[(size_t)(row0 + r) * 2048 + col] =
                f2bf(acc[fm][fn][r]);
        } else {
          ushort4 ov;
          ov.x = f2bf(acc[fm][fn][0]);
          ov.y = f2bf(acc[fm][fn][1]);
          ov.z = f2bf(acc[fm][fn][2]);
          ov.w = f2bf(acc[fm][fn][3]);
          *(ushort4*)((unsigned short*)Cout2 + (size_t)(col - 2048) * 4096 + row0) = ov;
        }
      }
    }
  }
}

// ---------------------------------------------------------------------------
// Flash attention (causal), swapped-operand, LDS-staged K/V, double-buffered.
// (unchanged)
// ---------------------------------------------------------------------------
__global__ __launch_bounds__(256) void attn_kernel(
    const unsigned short* __restrict__ qk, const unsigned short* __restrict__ vT,
    unsigned short* __restrict__ o) {
  const int T = 2048, C = 1024, QKS = 2048;
  const int tid = threadIdx.x;
  const int wave = tid >> 6, lane = tid & 63;
  const int lr = lane & 15, lg = lane >> 4;
  const int b = blockIdx.y >> 4, hh = blockIdx.y & 15;
  const size_t rowb = (size_t)b * T * QKS;
  const int qcol = hh * 64;
  const int kcol = 1024 + hh * 64;
  const int vrow0 = hh * 64;
  const size_t bT = (size_t)b * T;
  const int swe = (lr & 7) << 3;

  __shared__ __align__(16) unsigned short Ks[2][64 * 64];
  __shared__ __align__(16) unsigned short Vs[2][64 * 64];
  __shared__ __align__(16) unsigned short Ps[4][16][72];

  const int rw = tid >> 3;
  const int c8 = ((tid & 7) ^ (rw & 7)) << 3;

#pragma unroll 1
  for (int pass = 0; pass < 2; ++pass) {
    const int qt = (pass == 0) ? (int)blockIdx.x : (31 - (int)blockIdx.x);
    const int qbase = qt * 64 + wave * 16;
    const int trow = qbase + lr;

    U8 qf[2];
#pragma unroll
    for (int j = 0; j < 2; j++)
      qf[j].v = *(const bf16x8*)(qk + rowb + (size_t)trow * QKS + qcol + j * 32 + lg * 8);
    asm volatile("s_waitcnt vmcnt(0)" ::: "memory");

    async16(qk + rowb + (size_t)rw * QKS + kcol + c8, Ks[0] + tid * 8);
    async16(qk + rowb + (size_t)(32 + rw) * QKS + kcol + c8, Ks[0] + 2048 + tid * 8);
    async16(vT + (size_t)(vrow0 + rw) * 4096 + bT + c8, Vs[0] + tid * 8);
    async16(vT + (size_t)(vrow0 + 32 + rw) * 4096 + bT + c8, Vs[0] + 2048 + tid * 8);

    f32x4 oa[4] = {};
    float mrun = -1e30f, lsum = 0.0f;
    int cur = 0;

    for (int sb = 0; sb <= qt; ++sb) {
      if (sb < qt) {
        const int s1 = (sb + 1) * 64;
        const int nb = cur ^ 1;
        async16(qk + rowb + (size_t)(s1 + rw) * QKS + kcol + c8, Ks[nb] + tid * 8);
        async16(qk + rowb + (size_t)(s1 + 32 + rw) * QKS + kcol + c8, Ks[nb] + 2048 + tid * 8);
        async16(vT + (size_t)(vrow0 + rw) * 4096 + bT + s1 + c8, Vs[nb] + tid * 8);
        async16(vT + (size_t)(vrow0 + 32 + rw) * 4096 + bT + s1 + c8, Vs[nb] + 2048 + tid * 8);
        asm volatile("s_waitcnt vmcnt(4)" ::: "memory");
      } else {
        asm volatile("s_waitcnt vmcnt(0)" ::: "memory");
      }
      block_barrier();

      const unsigned short* Kc = Ks[cur];
      const unsigned short* Vc = Vs[cur];
      const int s0 = sb * 64;

      f32x4 sa[4] = {};
#pragma unroll
      for (int j = 0; j < 2; j++) {
#pragma unroll
        for (int mf = 0; mf < 4; mf++) {
          U8 kf;
          kf.v = *(const bf16x8*)(Kc + (mf * 16 + lr) * 64 + ((j * 32 + lg * 8) ^ swe));
          sa[mf] = __builtin_amdgcn_mfma_f32_16x16x32_bf16(kf.v, qf[j].v, sa[mf], 0, 0, 0);
        }
      }
      float sv[16];
#pragma unroll
      for (int mf = 0; mf < 4; mf++)
#pragma unroll
        for (int r = 0; r < 4; r++) sv[mf * 4 + r] = sa[mf][r] * 0.125f;

      if (sb == qt) {
#pragma unroll
        for (int mf = 0; mf < 4; mf++)
#pragma unroll
          for (int r = 0; r < 4; r++)
            if (s0 + mf * 16 + lg * 4 + r > trow) sv[mf * 4 + r] = -1e30f;
      }

      float tm = sv[0];
#pragma unroll
      for (int i = 1; i < 16; i++) tm = fmaxf(tm, sv[i]);
      tm = fmaxf(tm, __shfl_xor(tm, 16));
      tm = fmaxf(tm, __shfl_xor(tm, 32));

      if (!__all(tm <= mrun + 8.0f)) {
        const float mn = fmaxf(mrun, tm);
        const float corr = __expf(mrun - mn);
        lsum *= corr;
#pragma unroll
        for (int c = 0; c < 4; c++)
#pragma unroll
          for (int r = 0; r < 4; r++) oa[c][r] *= corr;
        mrun = mn;
      }

      float rs = 0.0f;
#pragma unroll
      for (int i = 0; i < 16; i++) {
        sv[i] = __expf(sv[i] - mrun);
        rs += sv[i];
      }
      rs += __shfl_xor(rs, 16);
      rs += __shfl_xor(rs, 32);
      lsum += rs;

#pragma unroll
      for (int mf = 0; mf < 4; mf++) {
        ushort4 w;
        w.x = f2bf(sv[mf * 4 + 0]);
        w.y = f2bf(sv[mf * 4 + 1]);
        w.z = f2bf(sv[mf * 4 + 2]);
        w.w = f2bf(sv[mf * 4 + 3]);
        *(ushort4*)&Ps[wave][lr][mf * 16 + lg * 4] = w;
      }
      asm volatile("" ::: "memory");
      U8 pb[2];
      pb[0].v = *(const bf16x8*)&Ps[wave][lr][lg * 8];
      pb[1].v = *(const bf16x8*)&Ps[wave][lr][32 + lg * 8];
      asm volatile("" ::: "memory");

#pragma unroll
      for (int c = 0; c < 4; c++) {
#pragma unroll
        for (int ks = 0; ks < 2; ks++) {
          U8 vf;
          vf.v = *(const bf16x8*)(Vc + (c * 16 + lr) * 64 + ((ks * 32 + lg * 8) ^ swe));
          oa[c] = __builtin_amdgcn_mfma_f32_16x16x32_bf16(vf.v, pb[ks].v, oa[c], 0, 0, 0);
        }
      }

      block_barrier();
      cur ^= 1;
    }

    const float inv = 1.0f / lsum;
#pragma unroll
    for (int c = 0; c < 4; c++) {
      ushort4 ov;
      ov.x = f2bf(oa[c][0] * inv);
      ov.y = f2bf(oa[c][1] * inv);
      ov.z = f2bf(oa[c][2] * inv);
      ov.w = f2bf(oa[c][3] * inv);
      *(ushort4*)(o + (size_t)(bT + trow) * C + hh * 64 + c * 16 + lg * 4) = ov;
    }
  }
}

// ---------------------------------------------------------------------------
// Orchestration
// ---------------------------------------------------------------------------
extern "C" void kernel_launch(void* const* d_in, const int* in_sizes, int n_in,
                              void* d_out, int out_size, void* d_ws, size_t ws_size,
                              hipStream_t stream) {
  (void)in_sizes; (void)n_in; (void)out_size; (void)ws_size;
  const int T = 2048, C = 1024, M = 2 * T, C4 = 4 * C;

  const float* x     = (const float*)d_in[0];
  const float* Wq    = (const float*)d_in[1];
  const float* Wk    = (const float*)d_in[2];
  const float* Wv    = (const float*)d_in[3];
  const float* Wproj = (const float*)d_in[4];
  const float* bproj = (const float*)d_in[5];
  const float* W1    = (const float*)d_in[6];
  const float* b1    = (const float*)d_in[7];
  const float* W2    = (const float*)d_in[8];
  const float* b2    = (const float*)d_in[9];
  const float* ln1g  = (const float*)d_in[10];
  const float* ln1b  = (const float*)d_in[11];
  const float* ln2g  = (const float*)d_in[12];
  const float* ln2b  = (const float*)d_in[13];
  float* out = (float*)d_out;

  char* ws = (char*)d_ws;
  const size_t MBy = (size_t)1 << 20;
  unsigned short* WqkvT = (unsigned short*)(ws + 0 * MBy);  // 6 MB [3072][1024]
  unsigned short* WqT = WqkvT;
  unsigned short* WkT = WqkvT + 1024 * 1024;
  unsigned short* WvT = WqkvT + 2048 * 1024;
  unsigned short* WpT = (unsigned short*)(ws + 6 * MBy);    // 2 MB
  unsigned short* W1T = (unsigned short*)(ws + 8 * MBy);    // 8 MB
  unsigned short* W2T = (unsigned short*)(ws + 16 * MBy);   // 8 MB
  unsigned short* h   = (unsigned short*)(ws + 24 * MBy);   // 8 MB  [4096][1024]
  unsigned short* qkb = (unsigned short*)(ws + 32 * MBy);   // 16 MB [4096][2048]
  unsigned short* vTb = (unsigned short*)(ws + 48 * MBy);   // 8 MB  [1024][4096]
  unsigned short* att = (unsigned short*)(ws + 56 * MBy);   // 8 MB
  float*          x1  = (float*)(ws + 64 * MBy);            // 16 MB
  unsigned short* h2  = att;                                // reuse
  unsigned short* ff1 = h;                                  // reuse h/qkb/vTb

  const dim3 tb(32, 8);
  transpose_w<<<dim3(2, 32, 16), tb, 0, stream>>>(Wq, WqT, 1024, 64);
  transpose_w<<<dim3(2, 32, 16), tb, 0, stream>>>(Wk, WkT, 1024, 64);
  transpose_w<<<dim3(2, 32, 16), tb, 0, stream>>>(Wv, WvT, 1024, 64);
  transpose_w<<<dim3(32, 32, 1), tb, 0, stream>>>(Wproj, WpT, 1024, 1024);
  transpose_w<<<dim3(128, 32, 1), tb, 0, stream>>>(W1, W1T, 1024, 4096);
  transpose_w<<<dim3(32, 128, 1), tb, 0, stream>>>(W2, W2T, 4096, 1024);

  ln_kernel<<<M, 256, 0, stream>>>(x, ln1g, ln1b, h);

  // Fused QKV (8-phase 256^2): N=3072; cols<2048 -> qkb, cols>=2048 -> vTb^T
  gemm8p<4><<<192, 512, 0, stream>>>(h, WqkvT, qkb, vTb, nullptr, M, 3072, C);

  attn_kernel<<<dim3(16, 32), 256, 0, stream>>>(qkb, vTb, att);

  // proj (+bias+resid) -> fp32, latency-pipelined 128^2
  gemm_pipe<<<256, 256, 0, stream>>>(att, WpT, x1, bproj, x, M, C, C);

  ln_kernel<<<M, 256, 0, stream>>>(x1, ln2g, ln2b, h2);

  // FFN1 (8-phase 256^2): relu(h2 @ W1 + b1) -> bf16
  gemm8p<2><<<256, 512, 0, stream>>>(h2, W1T, ff1, nullptr, b1, M, C4, C);

  // FFN2 (+bias+resid) -> fp32, latency-pipelined 128^2
  gemm_pipe<<<256, 256, 0, stream>>>(ff1, W2T, out, b2, x1, M, C, C4);
}

// Round 6
// 252.244 us; speedup vs baseline: 1.1452x; 1.0601x over previous
//
#include <hip/hip_runtime.h>

// ---------------------------------------------------------------------------
// Types / helpers
// ---------------------------------------------------------------------------
typedef __bf16 bf16x8 __attribute__((ext_vector_type(8)));
typedef float  f32x4  __attribute__((ext_vector_type(4)));

union U8 { bf16x8 v; __bf16 e[8]; unsigned short u[8]; };

__device__ __forceinline__ unsigned short f2bf(float f) {
  unsigned int u = __float_as_uint(f);
  unsigned int r = (u + 0x7FFFu + ((u >> 16) & 1u)) >> 16;  // RNE
  return (unsigned short)r;
}

__device__ __forceinline__ void async16(const void* g, void* l) {
  __builtin_amdgcn_global_load_lds(
      (__attribute__((address_space(1))) void*)(g),
      (__attribute__((address_space(3))) void*)(l), 16, 0, 0);
}

__device__ __forceinline__ void block_barrier() {
  asm volatile("" ::: "memory");
  __builtin_amdgcn_sched_barrier(0);
  __builtin_amdgcn_s_barrier();
  __builtin_amdgcn_sched_barrier(0);
  asm volatile("" ::: "memory");
}

// ---------------------------------------------------------------------------
// Batched transpose: in fp32 [batch][R][Cc] -> out bf16 [batch*Cc + c][R]
// ---------------------------------------------------------------------------
__global__ __launch_bounds__(256) void transpose_w(
    const float* __restrict__ in, unsigned short* __restrict__ out,
    int R, int Cc) {
  __shared__ float tile[32][33];
  const int batch = blockIdx.z;
  const float* ip = in + (size_t)batch * R * Cc;
  unsigned short* op = out + (size_t)batch * R * Cc;
  const int c0 = blockIdx.x * 32, r0 = blockIdx.y * 32;
  const int tx = threadIdx.x, ty = threadIdx.y;  // 32 x 8
#pragma unroll
  for (int i = 0; i < 32; i += 8)
    tile[ty + i][tx] = ip[(size_t)(r0 + ty + i) * Cc + c0 + tx];
  __syncthreads();
#pragma unroll
  for (int i = 0; i < 32; i += 8)
    op[(size_t)(c0 + ty + i) * R + r0 + tx] = f2bf(tile[tx][ty + i]);
}

// ---------------------------------------------------------------------------
// LayerNorm over rows of 1024, fp32 in -> bf16 out.
// ---------------------------------------------------------------------------
__global__ __launch_bounds__(256) void ln_kernel(
    const float* __restrict__ x, const float* __restrict__ g,
    const float* __restrict__ bta, unsigned short* __restrict__ out) {
  const int C = 1024;
  const int row = blockIdx.x, tid = threadIdx.x;
  const float4 v = ((const float4*)(x + (size_t)row * C))[tid];
  float s  = v.x + v.y + v.z + v.w;
  float ss = v.x * v.x + v.y * v.y + v.z * v.z + v.w * v.w;
#pragma unroll
  for (int off = 32; off > 0; off >>= 1) {
    s  += __shfl_down(s, off);
    ss += __shfl_down(ss, off);
  }
  __shared__ float r0[4], r1[4];
  const int wave = tid >> 6, lane = tid & 63;
  if (lane == 0) { r0[wave] = s; r1[wave] = ss; }
  __syncthreads();
  s  = r0[0] + r0[1] + r0[2] + r0[3];
  ss = r1[0] + r1[1] + r1[2] + r1[3];
  const float mu   = s * (1.0f / C);
  const float var  = ss * (1.0f / C) - mu * mu;
  const float rstd = rsqrtf(var + 1e-5f);
  const float4 gv = ((const float4*)g)[tid];
  const float4 bv = ((const float4*)bta)[tid];
  ushort4 o;
  o.x = f2bf((v.x - mu) * rstd * gv.x + bv.x);
  o.y = f2bf((v.y - mu) * rstd * gv.y + bv.y);
  o.z = f2bf((v.z - mu) * rstd * gv.z + bv.z);
  o.w = f2bf((v.w - mu) * rstd * gv.w + bv.w);
  ((ushort4*)(out + (size_t)row * C))[tid] = o;
}

// ---------------------------------------------------------------------------
// 128x64-tile latency GEMM for N=1024 shapes: 512 blocks = 2 blocks/CU
// (2 waves/SIMD TLP — the fix for round-5's 1-wave/SIMD latency wall).
// C[M][N] = A[M][K]*BT[N][K]^T + bias + resid -> fp32.
// BK=64, triple-buffered LDS (72 KB; 2 blocks x 72 = 144 <= 160 KB/CU),
// 2-tiles-ahead prefetch, counted vmcnt(6) (6 loads/tile), 1 barrier/tile.
// Chunk-XOR swizzle via pre-swizzled global source (round-5 verified:
// SQ_LDS_BANK_CONFLICT == 0). 4 waves = 2m x 2n; per-wave 64x32 out.
// ---------------------------------------------------------------------------
__global__ __launch_bounds__(256, 2) void gemm_lat2(
    const unsigned short* __restrict__ A, const unsigned short* __restrict__ BT,
    float* __restrict__ Cout, const float* __restrict__ bias,
    const float* __restrict__ resid, int M, int N, int K) {
  __shared__ __align__(16) unsigned short As[3][8192];  // [128 rows][64 k]
  __shared__ __align__(16) unsigned short Bs[3][4096];  // [64 rows][64 k]
  const int tid = threadIdx.x;
  const int lane = tid & 63, wave = tid >> 6;
  const int wm = wave >> 1, wn = wave & 1;
  const int lr = lane & 15, lg = lane >> 4;

  // XCD-bijective swizzle + GROUP_M=4 supertiling (nwg % 8 == 0)
  const int nwg = gridDim.x;
  const int cpx = nwg >> 3;
  const int swz = ((int)blockIdx.x & 7) * cpx + ((int)blockIdx.x >> 3);
  const int Nt = N >> 6;
  const int g4 = swz / (4 * Nt);
  const int rem = swz - g4 * 4 * Nt;
  const int m0 = (g4 * 4 + (rem & 3)) << 7;
  const int n0 = (rem >> 2) << 6;

  // staging: thread t covers A rows {t>>3 + 32j}, B rows {t>>3, t>>3+32};
  // one 16B chunk each, global chunk pre-swizzled (linear LDS = swizzled).
  const int srow = tid >> 3;
  const int sc = ((tid & 7) ^ (srow & 7)) << 3;
  const unsigned short* Ag = A + (size_t)(m0 + srow) * K + sc;
  const unsigned short* Bg = BT + (size_t)(n0 + srow) * K + sc;
  const size_t rskip = (size_t)32 * K;

  f32x4 acc[4][2] = {};
  const int nkt = K >> 6;

#define STG(T, B)                                                          \
  {                                                                        \
    const int kt_ = (T) << 6;                                              \
    _Pragma("unroll")                                                      \
    for (int j = 0; j < 4; ++j)                                            \
      async16(Ag + kt_ + (size_t)j * rskip, &As[B][j * 2048 + tid * 8]);   \
    async16(Bg + kt_, &Bs[B][tid * 8]);                                    \
    async16(Bg + kt_ + rskip, &Bs[B][2048 + tid * 8]);                     \
  }

  // prologue: stage tiles 0 and 1
  STG(0, 0);
  STG(1, 1);

  for (int t = 0; t < nkt; ++t) {
    const int buf = t % 3;
    if (t + 1 < nkt) asm volatile("s_waitcnt vmcnt(6)" ::: "memory");
    else             asm volatile("s_waitcnt vmcnt(0)" ::: "memory");
    block_barrier();
    if (t + 2 < nkt) {
      int sb = buf + 2; if (sb >= 3) sb -= 3;
      STG(t + 2, sb);
    }
#pragma unroll
    for (int kh = 0; kh < 2; ++kh) {
      const int kc = ((kh * 4 + lg) ^ (lr & 7)) << 3;
      bf16x8 afr[4], bfr[2];
#pragma unroll
      for (int fm = 0; fm < 4; fm++)
        afr[fm] = *(const bf16x8*)&As[buf][(wm * 64 + fm * 16 + lr) * 64 + kc];
#pragma unroll
      for (int fn = 0; fn < 2; fn++)
        bfr[fn] = *(const bf16x8*)&Bs[buf][(wn * 32 + fn * 16 + lr) * 64 + kc];
#pragma unroll
      for (int fm = 0; fm < 4; fm++)
#pragma unroll
        for (int fn = 0; fn < 2; fn++)
          acc[fm][fn] = __builtin_amdgcn_mfma_f32_16x16x32_bf16(
              afr[fm], bfr[fn], acc[fm][fn], 0, 0, 0);
    }
  }
#undef STG

#pragma unroll
  for (int fn = 0; fn < 2; fn++) {
    const int col = n0 + wn * 32 + fn * 16 + lr;
    const float bv = bias[col];
#pragma unroll
    for (int fm = 0; fm < 4; fm++) {
      const int row0 = m0 + wm * 64 + fm * 16 + lg * 4;
#pragma unroll
      for (int r = 0; r < 4; r++) {
        const size_t idx = (size_t)(row0 + r) * N + col;
        Cout[idx] = acc[fm][fn][r] + bv + resid[idx];
      }
    }
  }
}

// ---------------------------------------------------------------------------
// 256x256 8-phase deep-pipelined GEMM (unchanged).
// EPI: 2 = relu(+bias) -> bf16 ; 4 = QKV split
// ---------------------------------------------------------------------------
template <int EPI>
__global__ __launch_bounds__(512, 2) void gemm8p(
    const unsigned short* __restrict__ A, const unsigned short* __restrict__ BT,
    void* __restrict__ Cout, void* __restrict__ Cout2,
    const float* __restrict__ bias, int M, int N, int K) {
  __shared__ __align__(16) unsigned short As[2][2][8192];
  __shared__ __align__(16) unsigned short Bs[2][2][8192];
  const int tid = threadIdx.x;
  const int lane = tid & 63;
  const int wave = tid >> 6;
  const int wm = wave >> 2, wn = wave & 3;  // 2 x 4 wave grid
  const int lr = lane & 15, lg = lane >> 4;

  const int nwg = gridDim.x;
  const int cpx = nwg >> 3;
  const int swz = ((int)blockIdx.x & 7) * cpx + ((int)blockIdx.x >> 3);
  const int Nt = N >> 8;
  const int g4 = swz / (4 * Nt);
  const int rem = swz - g4 * 4 * Nt;
  const int m0 = (g4 * 4 + (rem & 3)) << 8;
  const int n0 = (rem >> 2) << 8;

  const int srow = tid >> 2;
  const int scg = ((tid & 3) ^ ((srow >> 1) & 3)) << 3;
  const unsigned short* Ag = A + (size_t)(m0 + srow) * K + scg;
  const unsigned short* Bg = BT + (size_t)(n0 + srow) * K + scg;
  const size_t rskip = (size_t)128 * K;
  const int l8 = tid * 8;

  const int kch = (lg ^ ((lr >> 1) & 3)) << 3;

  f32x4 acc[8][4] = {};
  bf16x8 afr[4], bfr[4];
  const int nkt = K >> 6;

  async16(Ag, &As[0][0][l8]);            async16(Ag + rskip, &As[0][0][l8 + 4096]);
  async16(Bg, &Bs[0][0][l8]);            async16(Bg + rskip, &Bs[0][0][l8 + 4096]);
  async16(Ag + 32, &As[0][1][l8]);       async16(Ag + 32 + rskip, &As[0][1][l8 + 4096]);
  async16(Bg + 32, &Bs[0][1][l8]);       async16(Bg + 32 + rskip, &Bs[0][1][l8 + 4096]);
  async16(Ag + 64, &As[1][0][l8]);       async16(Ag + 64 + rskip, &As[1][0][l8 + 4096]);
  async16(Bg + 64, &Bs[1][0][l8]);       async16(Bg + 64 + rskip, &Bs[1][0][l8 + 4096]);
  asm volatile("s_waitcnt vmcnt(4)" ::: "memory");
  block_barrier();

  for (int t = 0; t < nkt; ++t) {
    const int buf = t & 1, nbuf = buf ^ 1;
    const int kt1 = (t + 1) << 6, kt2 = (t + 2) << 6;
    const bool s1 = (t + 1 < nkt), s2 = (t + 2 < nkt);

    // ---- phase 1: ks=0, mh=0 ----
#pragma unroll
    for (int fm = 0; fm < 4; fm++)
      afr[fm] = *(const bf16x8*)&As[buf][0][(wm * 128 + fm * 16 + lr) * 32 + kch];
#pragma unroll
    for (int fn = 0; fn < 4; fn++)
      bfr[fn] = *(const bf16x8*)&Bs[buf][0][(wn * 64 + fn * 16 + lr) * 32 + kch];
    if (s1) {
      async16(Ag + kt1 + 32, &As[nbuf][1][l8]);
      async16(Ag + kt1 + 32 + rskip, &As[nbuf][1][l8 + 4096]);
    }
    block_barrier();
    __builtin_amdgcn_s_setprio(1);
#pragma unroll
    for (int fm = 0; fm < 4; fm++)
#pragma unroll
      for (int fn = 0; fn < 4; fn++)
        acc[fm][fn] = __builtin_amdgcn_mfma_f32_16x16x32_bf16(afr[fm], bfr[fn], acc[fm][fn], 0, 0, 0);
    __builtin_amdgcn_s_setprio(0);
    block_barrier();

    // ---- phase 2: ks=0, mh=1 ----
#pragma unroll
    for (int fm = 0; fm < 4; fm++)
      afr[fm] = *(const bf16x8*)&As[buf][0][(wm * 128 + 64 + fm * 16 + lr) * 32 + kch];
    if (s1) {
      async16(Bg + kt1 + 32, &Bs[nbuf][1][l8]);
      async16(Bg + kt1 + 32 + rskip, &Bs[nbuf][1][l8 + 4096]);
    }
    block_barrier();
    __builtin_amdgcn_s_setprio(1);
#pragma unroll
    for (int fm = 0; fm < 4; fm++)
#pragma unroll
      for (int fn = 0; fn < 4; fn++)
        acc[4 + fm][fn] = __builtin_amdgcn_mfma_f32_16x16x32_bf16(afr[fm], bfr[fn], acc[4 + fm][fn], 0, 0, 0);
    __builtin_amdgcn_s_setprio(0);
    block_barrier();

    // ---- phase 3: ks=1, mh=0 ----
#pragma unroll
    for (int fm = 0; fm < 4; fm++)
      afr[fm] = *(const bf16x8*)&As[buf][1][(wm * 128 + fm * 16 + lr) * 32 + kch];
#pragma unroll
    for (int fn = 0; fn < 4; fn++)
      bfr[fn] = *(const bf16x8*)&Bs[buf][1][(wn * 64 + fn * 16 + lr) * 32 + kch];
    if (s2) {
      async16(Ag + kt2, &As[buf][0][l8]);
      async16(Ag + kt2 + rskip, &As[buf][0][l8 + 4096]);
    }
    block_barrier();
    __builtin_amdgcn_s_setprio(1);
#pragma unroll
    for (int fm = 0; fm < 4; fm++)
#pragma unroll
      for (int fn = 0; fn < 4; fn++)
        acc[fm][fn] = __builtin_amdgcn_mfma_f32_16x16x32_bf16(afr[fm], bfr[fn], acc[fm][fn], 0, 0, 0);
    __builtin_amdgcn_s_setprio(0);
    block_barrier();

    // ---- phase 4: ks=1, mh=1 ----
#pragma unroll
    for (int fm = 0; fm < 4; fm++)
      afr[fm] = *(const bf16x8*)&As[buf][1][(wm * 128 + 64 + fm * 16 + lr) * 32 + kch];
    if (s2) {
      async16(Bg + kt2, &Bs[buf][0][l8]);
      async16(Bg + kt2 + rskip, &Bs[buf][0][l8 + 4096]);
    }
    block_barrier();
    __builtin_amdgcn_s_setprio(1);
#pragma unroll
    for (int fm = 0; fm < 4; fm++)
#pragma unroll
      for (int fn = 0; fn < 4; fn++)
        acc[4 + fm][fn] = __builtin_amdgcn_mfma_f32_16x16x32_bf16(afr[fm], bfr[fn], acc[4 + fm][fn], 0, 0, 0);
    __builtin_amdgcn_s_setprio(0);
    if (s2) asm volatile("s_waitcnt vmcnt(4)" ::: "memory");
    else    asm volatile("s_waitcnt vmcnt(0)" ::: "memory");
    block_barrier();
  }

#pragma unroll
  for (int fn = 0; fn < 4; fn++) {
    const int col = n0 + wn * 64 + fn * 16 + lr;
    float bv = 0.0f;
    if (EPI == 2) bv = bias[col];
#pragma unroll
    for (int fm = 0; fm < 8; fm++) {
      const int row0 = m0 + wm * 128 + fm * 16 + lg * 4;
      if (EPI == 2) {
#pragma unroll
        for (int r = 0; r < 4; r++)
          ((unsigned short*)Cout)[(size_t)(row0 + r) * N + col] =
              f2bf(fmaxf(acc[fm][fn][r] + bv, 0.0f));
      } else {  // EPI 4: QKV split
        if (col < 2048) {
#pragma unroll
          for (int r = 0; r < 4; r++)
            ((unsigned short*)Cout)[(size_t)(row0 + r) * 2048 + col] =
                f2bf(acc[fm][fn][r]);
        } else {
          ushort4 ov;
          ov.x = f2bf(acc[fm][fn][0]);
          ov.y = f2bf(acc[fm][fn][1]);
          ov.z = f2bf(acc[fm][fn][2]);
          ov.w = f2bf(acc[fm][fn][3]);
          *(ushort4*)((unsigned short*)Cout2 + (size_t)(col - 2048) * 4096 + row0) = ov;
        }
      }
    }
  }
}

// ---------------------------------------------------------------------------
// Flash attention (causal), swapped-operand, LDS-staged K/V, double-buffered.
// (unchanged)
// ---------------------------------------------------------------------------
__global__ __launch_bounds__(256) void attn_kernel(
    const unsigned short* __restrict__ qk, const unsigned short* __restrict__ vT,
    unsigned short* __restrict__ o) {
  const int T = 2048, C = 1024, QKS = 2048;
  const int tid = threadIdx.x;
  const int wave = tid >> 6, lane = tid & 63;
  const int lr = lane & 15, lg = lane >> 4;
  const int b = blockIdx.y >> 4, hh = blockIdx.y & 15;
  const size_t rowb = (size_t)b * T * QKS;
  const int qcol = hh * 64;
  const int kcol = 1024 + hh * 64;
  const int vrow0 = hh * 64;
  const size_t bT = (size_t)b * T;
  const int swe = (lr & 7) << 3;

  __shared__ __align__(16) unsigned short Ks[2][64 * 64];
  __shared__ __align__(16) unsigned short Vs[2][64 * 64];
  __shared__ __align__(16) unsigned short Ps[4][16][72];

  const int rw = tid >> 3;
  const int c8 = ((tid & 7) ^ (rw & 7)) << 3;

#pragma unroll 1
  for (int pass = 0; pass < 2; ++pass) {
    const int qt = (pass == 0) ? (int)blockIdx.x : (31 - (int)blockIdx.x);
    const int qbase = qt * 64 + wave * 16;
    const int trow = qbase + lr;

    U8 qf[2];
#pragma unroll
    for (int j = 0; j < 2; j++)
      qf[j].v = *(const bf16x8*)(qk + rowb + (size_t)trow * QKS + qcol + j * 32 + lg * 8);
    asm volatile("s_waitcnt vmcnt(0)" ::: "memory");

    async16(qk + rowb + (size_t)rw * QKS + kcol + c8, Ks[0] + tid * 8);
    async16(qk + rowb + (size_t)(32 + rw) * QKS + kcol + c8, Ks[0] + 2048 + tid * 8);
    async16(vT + (size_t)(vrow0 + rw) * 4096 + bT + c8, Vs[0] + tid * 8);
    async16(vT + (size_t)(vrow0 + 32 + rw) * 4096 + bT + c8, Vs[0] + 2048 + tid * 8);

    f32x4 oa[4] = {};
    float mrun = -1e30f, lsum = 0.0f;
    int cur = 0;

    for (int sb = 0; sb <= qt; ++sb) {
      if (sb < qt) {
        const int s1 = (sb + 1) * 64;
        const int nb = cur ^ 1;
        async16(qk + rowb + (size_t)(s1 + rw) * QKS + kcol + c8, Ks[nb] + tid * 8);
        async16(qk + rowb + (size_t)(s1 + 32 + rw) * QKS + kcol + c8, Ks[nb] + 2048 + tid * 8);
        async16(vT + (size_t)(vrow0 + rw) * 4096 + bT + s1 + c8, Vs[nb] + tid * 8);
        async16(vT + (size_t)(vrow0 + 32 + rw) * 4096 + bT + s1 + c8, Vs[nb] + 2048 + tid * 8);
        asm volatile("s_waitcnt vmcnt(4)" ::: "memory");
      } else {
        asm volatile("s_waitcnt vmcnt(0)" ::: "memory");
      }
      block_barrier();

      const unsigned short* Kc = Ks[cur];
      const unsigned short* Vc = Vs[cur];
      const int s0 = sb * 64;

      f32x4 sa[4] = {};
#pragma unroll
      for (int j = 0; j < 2; j++) {
#pragma unroll
        for (int mf = 0; mf < 4; mf++) {
          U8 kf;
          kf.v = *(const bf16x8*)(Kc + (mf * 16 + lr) * 64 + ((j * 32 + lg * 8) ^ swe));
          sa[mf] = __builtin_amdgcn_mfma_f32_16x16x32_bf16(kf.v, qf[j].v, sa[mf], 0, 0, 0);
        }
      }
      float sv[16];
#pragma unroll
      for (int mf = 0; mf < 4; mf++)
#pragma unroll
        for (int r = 0; r < 4; r++) sv[mf * 4 + r] = sa[mf][r] * 0.125f;

      if (sb == qt) {
#pragma unroll
        for (int mf = 0; mf < 4; mf++)
#pragma unroll
          for (int r = 0; r < 4; r++)
            if (s0 + mf * 16 + lg * 4 + r > trow) sv[mf * 4 + r] = -1e30f;
      }

      float tm = sv[0];
#pragma unroll
      for (int i = 1; i < 16; i++) tm = fmaxf(tm, sv[i]);
      tm = fmaxf(tm, __shfl_xor(tm, 16));
      tm = fmaxf(tm, __shfl_xor(tm, 32));

      if (!__all(tm <= mrun + 8.0f)) {
        const float mn = fmaxf(mrun, tm);
        const float corr = __expf(mrun - mn);
        lsum *= corr;
#pragma unroll
        for (int c = 0; c < 4; c++)
#pragma unroll
          for (int r = 0; r < 4; r++) oa[c][r] *= corr;
        mrun = mn;
      }

      float rs = 0.0f;
#pragma unroll
      for (int i = 0; i < 16; i++) {
        sv[i] = __expf(sv[i] - mrun);
        rs += sv[i];
      }
      rs += __shfl_xor(rs, 16);
      rs += __shfl_xor(rs, 32);
      lsum += rs;

#pragma unroll
      for (int mf = 0; mf < 4; mf++) {
        ushort4 w;
        w.x = f2bf(sv[mf * 4 + 0]);
        w.y = f2bf(sv[mf * 4 + 1]);
        w.z = f2bf(sv[mf * 4 + 2]);
        w.w = f2bf(sv[mf * 4 + 3]);
        *(ushort4*)&Ps[wave][lr][mf * 16 + lg * 4] = w;
      }
      asm volatile("" ::: "memory");
      U8 pb[2];
      pb[0].v = *(const bf16x8*)&Ps[wave][lr][lg * 8];
      pb[1].v = *(const bf16x8*)&Ps[wave][lr][32 + lg * 8];
      asm volatile("" ::: "memory");

#pragma unroll
      for (int c = 0; c < 4; c++) {
#pragma unroll
        for (int ks = 0; ks < 2; ks++) {
          U8 vf;
          vf.v = *(const bf16x8*)(Vc + (c * 16 + lr) * 64 + ((ks * 32 + lg * 8) ^ swe));
          oa[c] = __builtin_amdgcn_mfma_f32_16x16x32_bf16(vf.v, pb[ks].v, oa[c], 0, 0, 0);
        }
      }

      block_barrier();
      cur ^= 1;
    }

    const float inv = 1.0f / lsum;
#pragma unroll
    for (int c = 0; c < 4; c++) {
      ushort4 ov;
      ov.x = f2bf(oa[c][0] * inv);
      ov.y = f2bf(oa[c][1] * inv);
      ov.z = f2bf(oa[c][2] * inv);
      ov.w = f2bf(oa[c][3] * inv);
      *(ushort4*)(o + (size_t)(bT + trow) * C + hh * 64 + c * 16 + lg * 4) = ov;
    }
  }
}

// ---------------------------------------------------------------------------
// Orchestration
// ---------------------------------------------------------------------------
extern "C" void kernel_launch(void* const* d_in, const int* in_sizes, int n_in,
                              void* d_out, int out_size, void* d_ws, size_t ws_size,
                              hipStream_t stream) {
  (void)in_sizes; (void)n_in; (void)out_size; (void)ws_size;
  const int T = 2048, C = 1024, M = 2 * T, C4 = 4 * C;

  const float* x     = (const float*)d_in[0];
  const float* Wq    = (const float*)d_in[1];
  const float* Wk    = (const float*)d_in[2];
  const float* Wv    = (const float*)d_in[3];
  const float* Wproj = (const float*)d_in[4];
  const float* bproj = (const float*)d_in[5];
  const float* W1    = (const float*)d_in[6];
  const float* b1    = (const float*)d_in[7];
  const float* W2    = (const float*)d_in[8];
  const float* b2    = (const float*)d_in[9];
  const float* ln1g  = (const float*)d_in[10];
  const float* ln1b  = (const float*)d_in[11];
  const float* ln2g  = (const float*)d_in[12];
  const float* ln2b  = (const float*)d_in[13];
  float* out = (float*)d_out;

  char* ws = (char*)d_ws;
  const size_t MBy = (size_t)1 << 20;
  unsigned short* WqkvT = (unsigned short*)(ws + 0 * MBy);  // 6 MB [3072][1024]
  unsigned short* WqT = WqkvT;
  unsigned short* WkT = WqkvT + 1024 * 1024;
  unsigned short* WvT = WqkvT + 2048 * 1024;
  unsigned short* WpT = (unsigned short*)(ws + 6 * MBy);    // 2 MB
  unsigned short* W1T = (unsigned short*)(ws + 8 * MBy);    // 8 MB
  unsigned short* W2T = (unsigned short*)(ws + 16 * MBy);   // 8 MB
  unsigned short* h   = (unsigned short*)(ws + 24 * MBy);   // 8 MB  [4096][1024]
  unsigned short* qkb = (unsigned short*)(ws + 32 * MBy);   // 16 MB [4096][2048]
  unsigned short* vTb = (unsigned short*)(ws + 48 * MBy);   // 8 MB  [1024][4096]
  unsigned short* att = (unsigned short*)(ws + 56 * MBy);   // 8 MB
  float*          x1  = (float*)(ws + 64 * MBy);            // 16 MB
  unsigned short* h2  = att;                                // reuse
  unsigned short* ff1 = h;                                  // reuse h/qkb/vTb

  const dim3 tb(32, 8);
  transpose_w<<<dim3(2, 32, 16), tb, 0, stream>>>(Wq, WqT, 1024, 64);
  transpose_w<<<dim3(2, 32, 16), tb, 0, stream>>>(Wk, WkT, 1024, 64);
  transpose_w<<<dim3(2, 32, 16), tb, 0, stream>>>(Wv, WvT, 1024, 64);
  transpose_w<<<dim3(32, 32, 1), tb, 0, stream>>>(Wproj, WpT, 1024, 1024);
  transpose_w<<<dim3(128, 32, 1), tb, 0, stream>>>(W1, W1T, 1024, 4096);
  transpose_w<<<dim3(32, 128, 1), tb, 0, stream>>>(W2, W2T, 4096, 1024);

  ln_kernel<<<M, 256, 0, stream>>>(x, ln1g, ln1b, h);

  // Fused QKV (8-phase 256^2): N=3072; cols<2048 -> qkb, cols>=2048 -> vTb^T
  gemm8p<4><<<192, 512, 0, stream>>>(h, WqkvT, qkb, vTb, nullptr, M, 3072, C);

  attn_kernel<<<dim3(16, 32), 256, 0, stream>>>(qkb, vTb, att);

  // proj (+bias+resid) -> fp32, 128x64 tiles, 2 blocks/CU
  gemm_lat2<<<512, 256, 0, stream>>>(att, WpT, x1, bproj, x, M, C, C);

  ln_kernel<<<M, 256, 0, stream>>>(x1, ln2g, ln2b, h2);

  // FFN1 (8-phase 256^2): relu(h2 @ W1 + b1) -> bf16
  gemm8p<2><<<256, 512, 0, stream>>>(h2, W1T, ff1, nullptr, b1, M, C4, C);

  // FFN2 (+bias+resid) -> fp32, 128x64 tiles, 2 blocks/CU
  gemm_lat2<<<512, 256, 0, stream>>>(ff1, W2T, out, b2, x1, M, C, C4);
}